// Round 4
// baseline (116.306 us; speedup 1.0000x reference)
//
#include <hip/hip_runtime.h>
#include <stdint.h>

#define T_STEPS 32
#define DECAY   0.951229424500714f    // exp(-1/20)
#define DECAY16 0.449328964117222f    // exp(-16/20)

typedef __attribute__((ext_vector_type(4))) float f32x4;
typedef __attribute__((ext_vector_type(8))) short bf16x8;

typedef const void __attribute__((address_space(1)))* gptr_t;
typedef void __attribute__((address_space(3)))* sptr_t;

__device__ __forceinline__ unsigned short f2bf(float f) {
    unsigned u = __builtin_bit_cast(unsigned, f);
    return (unsigned short)((u + 0x7FFFu + ((u >> 16) & 1u)) >> 16);
}

// blocks [0, mBlocks): temporal leaky reduce x[M][T][D] -> mem[M][D] (bf16 bits)
// blocks [mBlocks, ...): convert W fp32 -> bf16
__global__ __launch_bounds__(256) void prep_kernel(
    const float* __restrict__ x, const float* __restrict__ W,
    unsigned short* __restrict__ mem, unsigned short* __restrict__ Wb,
    int mBlocks, int M, int D)
{
    if ((int)blockIdx.x < mBlocks) {
        int idx = blockIdx.x * 256 + threadIdx.x;   // one per 4 floats of mem
        int perRow = D >> 2;                        // float4 per row
        int m = idx / perRow;
        int d4 = idx - m * perRow;
        if (m >= M) return;
        const f32x4* xr = (const f32x4*)(x + (size_t)m * T_STEPS * D) + d4;
        // two independent 16-long chains for load ILP; result = hi*d^16 + lo
        f32x4 accH = {0.f, 0.f, 0.f, 0.f};
        f32x4 accL = {0.f, 0.f, 0.f, 0.f};
        #pragma unroll
        for (int t = 0; t < 16; ++t) {
            f32x4 vh = __builtin_nontemporal_load(&xr[(size_t)t * perRow]);
            f32x4 vl = __builtin_nontemporal_load(&xr[(size_t)(t + 16) * perRow]);
            accH = accH * DECAY + vh;
            accL = accL * DECAY + vl;
        }
        f32x4 acc = accH * DECAY16 + accL;
        ushort4 o;
        o.x = f2bf(acc.x); o.y = f2bf(acc.y); o.z = f2bf(acc.z); o.w = f2bf(acc.w);
        *(ushort4*)(mem + (size_t)idx * 4) = o;
    } else {
        int idx = (blockIdx.x - mBlocks) * 256 + threadIdx.x;
        f32x4 v = ((const f32x4*)W)[idx];
        ushort4 o;
        o.x = f2bf(v.x); o.y = f2bf(v.y); o.z = f2bf(v.z); o.w = f2bf(v.w);
        *(ushort4*)(Wb + (size_t)idx * 4) = o;
    }
}

// C[M][N] = A[M][K] @ B[N][K]^T + bias, bf16 inputs, fp32 out
// 128x128 tile, BK=32, 4 waves (2x2) each 64x64: 16 MFMA : 8 ds_read_b128.
// Quad-buffered LDS, depth-3 prefetch, counted vmcnt (never 0 in loop).
#define BM 128
#define BN 128
#define BK 32

__global__ __launch_bounds__(256) void gemm_kernel(
    const unsigned short* __restrict__ A,    // mem bf16 [M][K]
    const unsigned short* __restrict__ Bw,   // W bf16 [N][K]
    const float* __restrict__ bias,          // [N]
    float* __restrict__ C,                   // [M][N]
    int M, int N, int K)
{
    __shared__ unsigned short As[4][BM][BK];   // 4 x 8 KiB
    __shared__ unsigned short Bs[4][BN][BK];   // 4 x 8 KiB

    // XCD-aware swizzle (grid=256, 256%8==0 -> bijective)
    int nwg = gridDim.x;
    int cpx = nwg >> 3;
    int bid = (int)blockIdx.x;
    int wg  = (bid & 7) * cpx + (bid >> 3);

    int nbn = N / BN;
    int bm = wg / nbn;
    int bn = wg % nbn;

    int tid  = threadIdx.x;
    int lane = tid & 63;
    int wid  = tid >> 6;         // 0..3
    int wr   = wid >> 1;         // wave row block (64 rows)
    int wc   = wid & 1;          // wave col block (64 cols)

    // staging: per inst, LDS dest byte = 16*tid within each half (linear, rule 21)
    int srow = tid >> 2;         // 0..63
    int scol = (tid & 3) << 3;   // bf16 elems 0,8,16,24

    const unsigned short* Ag0 = A  + (size_t)(bm * BM + srow) * K + scol;
    const unsigned short* Ag1 = A  + (size_t)(bm * BM + 64 + srow) * K + scol;
    const unsigned short* Bg0 = Bw + (size_t)(bn * BN + srow) * K + scol;
    const unsigned short* Bg1 = Bw + (size_t)(bn * BN + 64 + srow) * K + scol;

    f32x4 acc[4][4] = {};

    int fr = lane & 15;          // row within 16x16 fragment
    int fk = (lane >> 4) << 3;   // k offset (8 bf16 per lane)

    auto stage = [&](int b, int kt) {
        int k0 = kt * BK;
        __builtin_amdgcn_global_load_lds((gptr_t)(Ag0 + k0), (sptr_t)(&As[b][srow][scol]),      16, 0, 0);
        __builtin_amdgcn_global_load_lds((gptr_t)(Ag1 + k0), (sptr_t)(&As[b][64 + srow][scol]), 16, 0, 0);
        __builtin_amdgcn_global_load_lds((gptr_t)(Bg0 + k0), (sptr_t)(&Bs[b][srow][scol]),      16, 0, 0);
        __builtin_amdgcn_global_load_lds((gptr_t)(Bg1 + k0), (sptr_t)(&Bs[b][64 + srow][scol]), 16, 0, 0);
    };

    int nk = K / BK;             // 32

    stage(0, 0);
    stage(1, 1);
    stage(2, 2);                                       // 12 loads outstanding
    asm volatile("s_waitcnt vmcnt(8)" ::: "memory");   // buf0 landed
    __builtin_amdgcn_s_barrier();

    for (int kt = 0; kt < nk; ++kt) {
        int cur = kt & 3;
        if (kt + 3 < nk) stage((kt + 3) & 3, kt + 3);  // keep pipeline 3 deep

        bf16x8 a0 = *(const bf16x8*)&As[cur][wr * 64 +      fr][fk];
        bf16x8 a1 = *(const bf16x8*)&As[cur][wr * 64 + 16 + fr][fk];
        bf16x8 a2 = *(const bf16x8*)&As[cur][wr * 64 + 32 + fr][fk];
        bf16x8 a3 = *(const bf16x8*)&As[cur][wr * 64 + 48 + fr][fk];
        bf16x8 b0 = *(const bf16x8*)&Bs[cur][wc * 64 +      fr][fk];
        bf16x8 b1 = *(const bf16x8*)&Bs[cur][wc * 64 + 16 + fr][fk];
        bf16x8 b2 = *(const bf16x8*)&Bs[cur][wc * 64 + 32 + fr][fk];
        bf16x8 b3 = *(const bf16x8*)&Bs[cur][wc * 64 + 48 + fr][fk];

        #pragma unroll
        for (int mi = 0; mi < 4; ++mi) {
            bf16x8 am = (mi == 0) ? a0 : (mi == 1) ? a1 : (mi == 2) ? a2 : a3;
            acc[mi][0] = __builtin_amdgcn_mfma_f32_16x16x32_bf16(am, b0, acc[mi][0], 0, 0, 0);
            acc[mi][1] = __builtin_amdgcn_mfma_f32_16x16x32_bf16(am, b1, acc[mi][1], 0, 0, 0);
            acc[mi][2] = __builtin_amdgcn_mfma_f32_16x16x32_bf16(am, b2, acc[mi][2], 0, 0, 0);
            acc[mi][3] = __builtin_amdgcn_mfma_f32_16x16x32_bf16(am, b3, acc[mi][3], 0, 0, 0);
        }

        // wait until next buffer's stage has landed; never drain to 0 mid-loop
        if (kt + 3 < nk) {
            asm volatile("s_waitcnt vmcnt(8)" ::: "memory");   // stage(kt+1) done
        } else if (kt + 2 < nk) {
            asm volatile("s_waitcnt vmcnt(4)" ::: "memory");
        } else if (kt + 1 < nk) {
            asm volatile("s_waitcnt vmcnt(0)" ::: "memory");
        }
        if (kt + 1 < nk) __builtin_amdgcn_s_barrier();
    }

    // C/D layout: col = lane&15, row = (lane>>4)*4 + reg
    int fc  = lane & 15;
    int fq  = (lane >> 4) << 2;
    int row0 = bm * BM + wr * 64;
    int col0 = bn * BN + wc * 64;
    #pragma unroll
    for (int mi = 0; mi < 4; ++mi) {
        #pragma unroll
        for (int ni = 0; ni < 4; ++ni) {
            int col = col0 + ni * 16 + fc;
            float bv = bias[col];
            #pragma unroll
            for (int r = 0; r < 4; ++r) {
                int row = row0 + mi * 16 + fq + r;
                C[(size_t)row * N + col] = acc[mi][ni][r] + bv;
            }
        }
    }
}

extern "C" void kernel_launch(void* const* d_in, const int* in_sizes, int n_in,
                              void* d_out, int out_size, void* d_ws, size_t ws_size,
                              hipStream_t stream) {
    const float* x    = (const float*)d_in[0];
    const float* W    = (const float*)d_in[1];
    const float* bias = (const float*)d_in[2];
    float* out = (float*)d_out;

    int Dout = in_sizes[2];                   // 1024
    int Din  = in_sizes[1] / Dout;            // 1024
    int M    = in_sizes[0] / (T_STEPS * Din); // 4096 (= B*S)

    unsigned short* mem = (unsigned short*)d_ws;                      // M*Din bf16
    unsigned short* Wb  = (unsigned short*)d_ws + (size_t)M * Din;    // Dout*Din bf16

    int mBlocks = (M * Din) / (4 * 256);      // 4096
    int wBlocks = (Dout * Din) / (4 * 256);   // 1024
    prep_kernel<<<mBlocks + wBlocks, 256, 0, stream>>>(x, W, mem, Wb, mBlocks, M, Din);

    int grid = (M / BM) * (Dout / BN);        // 256
    gemm_kernel<<<grid, 256, 0, stream>>>(mem, Wb, bias, out, M, Dout, Din);
}